// Round 17
// baseline (312.092 us; speedup 1.0000x reference)
//
#include <hip/hip_runtime.h>

// SparseWeights: y = x @ (W_dense + scatter(sparse))^T + bias
// Round 17: r16 base (best timed: 297.8us) + (1) restore setprio around MFMA
// quadrants (r7/r14 — the two best GEMMs — both had it; its removal was
// bundled into r16 and likely cost a few us), (2) fuse the two f32->bf16
// cvt prepasses into one kernel (independent outputs; scatter stays separate
// as it must follow W-cvt). Float4 swapped-operand epilogue kept from r16.

typedef __attribute__((ext_vector_type(8))) __bf16 bf16x8;
typedef __attribute__((ext_vector_type(4))) float f32x4;
typedef __attribute__((ext_vector_type(8))) unsigned short u16x8;

#define BARRIER()   asm volatile("s_barrier" ::: "memory")
#define WAITLGKM(n) asm volatile("s_waitcnt lgkmcnt(" #n ")" ::: "memory")
#define WAITVM0()   asm volatile("s_waitcnt vmcnt(0)" ::: "memory")
#define SCHED0()    __builtin_amdgcn_sched_barrier(0)

__device__ __forceinline__ unsigned short f2bf(float f) {
  unsigned int u = __builtin_bit_cast(unsigned int, f);
  u += 0x7FFFu + ((u >> 16) & 1u);   // round-to-nearest-even
  return (unsigned short)(u >> 16);
}

// ---- prepass 1/2: fused f32 -> bf16 convert of W and x (vectorized x8) ----
__global__ __launch_bounds__(256) void cvt_both(
    const float* __restrict__ sw, unsigned short* __restrict__ dw2,
    const float* __restrict__ sx, unsigned short* __restrict__ dx2,
    long w8, long n8) {
  long i = (long)blockIdx.x * blockDim.x + threadIdx.x;
  const long stride = (long)gridDim.x * blockDim.x;
  for (; i < n8; i += stride) {
    const float* s = (i < w8) ? sw + i * 8 : sx + (i - w8) * 8;
    unsigned short* d = (i < w8) ? dw2 + i * 8 : dx2 + (i - w8) * 8;
    const float4* sp = (const float4*)s;
    float4 a = sp[0];
    float4 b = sp[1];
    u16x8 o;
    o[0] = f2bf(a.x); o[1] = f2bf(a.y); o[2] = f2bf(a.z); o[3] = f2bf(a.w);
    o[4] = f2bf(b.x); o[5] = f2bf(b.y); o[6] = f2bf(b.z); o[7] = f2bf(b.w);
    *(u16x8*)d = o;
  }
}

// ---- prepass 2/2: scatter sparse values into bf16 W (after W-cvt) ----
__global__ __launch_bounds__(256) void sparse_scatter(
    const float* __restrict__ dense, const float* __restrict__ vals,
    const int* __restrict__ rows, const int* __restrict__ cols,
    unsigned short* __restrict__ Wb, int nnz, int K) {
  int i = blockIdx.x * blockDim.x + threadIdx.x;
  if (i < nnz) {
    size_t off = (size_t)rows[i] * (size_t)K + (size_t)cols[i];
    Wb[off] = f2bf(dense[off] + vals[i]);
  }
}

// =====================================================================
// 256x256 GEMM, 512 threads = 8 waves (2Mx4N), wave tile 128x64 =
// acc[8][4] of 16x16x32 frags, BK=64 (kk=0,1). LDS 2 x (A 32K + B 32K)
// = 128 KiB dbuf. Rows 128 B = 8 quads; LDS quad q of row r holds global
// quad q^(r&7) (pre-swizzled source, swizzled read; 0 conflicts r6-r16).
//
// Lead-1 pipeline per tile t (buf = t&1) — identical to r14/r16:
//  X1 (end of prev iter): MFMA Q11(t-1); read a03(t)+b01(t) [12];
//     stage-all(t+2) [8 gl_lds]
//  X2: read b23(t) [4]; lgkm(4) {drains 12, keeps b23}; Q00
//  X3: lgkm(0) {b23, covered}; Q01; read a47(t) [8] into shared A-buf
//  X4: lgkm(0) {a47}; Q10; vmcnt(0) {stage(t+1), 1 iter old}; BARRIER
//
// MFMA operands swapped (r16): acc = mfma(b, a, acc) -> lane holds 4
// consecutive C columns -> float4 C-stores. setprio restored (r7/r14).
// =====================================================================
__global__ __launch_bounds__(512, 2) void gemm17(
    const unsigned short* __restrict__ A,   // [Tm][K] bf16
    const unsigned short* __restrict__ B,   // [Mn][K] bf16
    const float* __restrict__ bias,
    float* __restrict__ C,
    int Tm, int Mn, int K) {
  extern __shared__ __align__(16) char smem[];   // 2 x 65536

  const int tid  = threadIdx.x;
  const int lane = tid & 63;
  const int wid  = tid >> 6;
  const int wm = (wid >> 2) * 128;
  const int wn = (wid & 3) * 64;

  // T1: XCD-aware bijective swizzle (nwg = 512, % 8 == 0)
  const int nwg = gridDim.x;
  int bid = blockIdx.x;
  if ((nwg & 7) == 0) bid = (bid & 7) * (nwg >> 3) + (bid >> 3);
  const int ntn = Mn >> 8;
  const int bm0 = (bid / ntn) << 8;
  const int bn0 = (bid % ntn) << 8;

  const int NT = K >> 6;             // K-tiles of 64

  // ---- staging (identical mapping to r6-r16, correctness-verified) ----
  const int sr  = tid >> 3;                          // 0..63
  const int gq8 = ((tid & 7) ^ (sr & 7)) * 8;        // pre-swizzled elem off
  const unsigned short* Asrc = A + (size_t)(bm0 + sr) * K + gq8;
  const unsigned short* Bsrc = B + (size_t)(bn0 + sr) * K + gq8;
  const size_t r64 = (size_t)64 * K;
  const int ldst = tid * 16;

#define STAGEH(SRC, H, LDSB, KOFF) do {                                          \
    __builtin_amdgcn_global_load_lds(                                            \
      (const __attribute__((address_space(1))) void*)((SRC) + (size_t)(H)*2*r64 + (KOFF)), \
      (__attribute__((address_space(3))) void*)(smem + (LDSB) + ldst), 16, 0, 0);\
    __builtin_amdgcn_global_load_lds(                                            \
      (const __attribute__((address_space(1))) void*)((SRC) + (size_t)(H)*2*r64 + r64 + (KOFF)), \
      (__attribute__((address_space(3))) void*)(smem + (LDSB) + 8192 + ldst), 16, 0, 0); \
  } while (0)

#define STAGEALL(NB, KO) do {                                                    \
    STAGEH(Asrc, 0, (NB), (KO));                                                 \
    STAGEH(Asrc, 1, (NB) + 16384, (KO));                                         \
    STAGEH(Bsrc, 0, (NB) + 32768, (KO));                                         \
    STAGEH(Bsrc, 1, (NB) + 49152, (KO));                                         \
  } while (0)

  // ---- read offsets: frag (row R, kk, cq) -> byte R*128 + ((kk*4+cq)^(R&7))*16
  const int fr = lane & 15, cq = lane >> 4;
  const int f7 = fr & 7;
  const int q0 = ((cq ^ f7) << 4);          // kk = 0
  const int q1 = (((4 + cq) ^ f7) << 4);    // kk = 1
  const int arow = (wm + fr) * 128;
  const int brow = (wn + fr) * 128;

  f32x4 acc[8][4] = {};
  bf16x8 Aq0[4], Aq1[4];                    // shared a03 / a47
  bf16x8 b1q0[2], b1q1[2], b2q0[2], b2q1[2];

#define READ12(BUF) do {                                                         \
    _Pragma("unroll")                                                            \
    for (int m = 0; m < 4; ++m) {                                                \
      Aq0[m] = *(const bf16x8*)((BUF) + arow + m * 2048 + q0);                   \
      Aq1[m] = *(const bf16x8*)((BUF) + arow + m * 2048 + q1);                   \
    }                                                                            \
    _Pragma("unroll")                                                            \
    for (int n = 0; n < 2; ++n) {                                                \
      b1q0[n] = *(const bf16x8*)((BUF) + 32768 + brow + n * 2048 + q0);          \
      b1q1[n] = *(const bf16x8*)((BUF) + 32768 + brow + n * 2048 + q1);          \
    }                                                                            \
  } while (0)

#define READB23(BUF) do {                                                        \
    _Pragma("unroll")                                                            \
    for (int n = 0; n < 2; ++n) {                                                \
      b2q0[n] = *(const bf16x8*)((BUF) + 32768 + brow + (n + 2) * 2048 + q0);    \
      b2q1[n] = *(const bf16x8*)((BUF) + 32768 + brow + (n + 2) * 2048 + q1);    \
    }                                                                            \
  } while (0)

#define READA47(BUF) do {                                                        \
    _Pragma("unroll")                                                            \
    for (int m = 0; m < 4; ++m) {                                                \
      Aq0[m] = *(const bf16x8*)((BUF) + arow + (m + 4) * 2048 + q0);             \
      Aq1[m] = *(const bf16x8*)((BUF) + arow + (m + 4) * 2048 + q1);             \
    }                                                                            \
  } while (0)

// Swapped operands + setprio: D = b x a = C^T fragment.
#define QUAD(MB, NB, BQ0, BQ1) do {                                              \
    __builtin_amdgcn_s_setprio(1);                                               \
    _Pragma("unroll")                                                            \
    for (int m = 0; m < 4; ++m)                                                  \
      _Pragma("unroll")                                                          \
      for (int n = 0; n < 2; ++n) {                                              \
        acc[m+(MB)][n+(NB)] = __builtin_amdgcn_mfma_f32_16x16x32_bf16(           \
            BQ0[n], Aq0[m], acc[m+(MB)][n+(NB)], 0, 0, 0);                       \
        acc[m+(MB)][n+(NB)] = __builtin_amdgcn_mfma_f32_16x16x32_bf16(           \
            BQ1[n], Aq1[m], acc[m+(MB)][n+(NB)], 0, 0, 0);                       \
      }                                                                          \
    __builtin_amdgcn_s_setprio(0);                                               \
  } while (0)

  // ---- prologue: stage tile 0; publish; lead-1 reads of tile 0; stage 1 ----
  STAGEALL(0, 0);
  WAITVM0();
  BARRIER();
  READ12(smem);
  SCHED0();
  if (NT > 1) STAGEALL(65536, 64);
  SCHED0();

  for (int t = 0; t < NT; ++t) {
    const char* buf = smem + (t & 1) * 65536;

    // ---- X2: b23 reads; counted lgkm(4); Q00 ----
    READB23(buf);
    SCHED0();
    WAITLGKM(4);          // drain a03+b01 (12); b23 (4) stays in flight
    SCHED0();
    QUAD(0, 0, b1q0, b1q1);
    SCHED0();

    // ---- X3: lgkm(0) (b23, covered by Q00); Q01; a47 reads after ----
    WAITLGKM(0);
    SCHED0();
    QUAD(0, 2, b2q0, b2q1);
    SCHED0();
    READA47(buf);         // overwrites shared A after Q01 latched a03
    SCHED0();

    // ---- X4: lgkm(0) (a47); Q10; drain stages; publish ----
    WAITLGKM(0);
    SCHED0();
    QUAD(4, 0, b1q0, b1q1);
    WAITVM0();            // stage(t+1): issued one full iter ago -> free
    BARRIER();

    // ---- X1 of next frame: Q11; lead-1 reads(t+1); stage(t+2) ----
    QUAD(4, 2, b2q0, b2q1);
    SCHED0();
    if (t + 1 < NT) {
      const char* nbuf = smem + ((t + 1) & 1) * 65536;
      READ12(nbuf);       // overwrites A (a47 latched by Q11) + b01
      SCHED0();
      if (t + 2 < NT) STAGEALL((t & 1) * 65536, (t + 2) * 64);
      SCHED0();
    }
  }
#undef QUAD
#undef READA47
#undef READB23
#undef READ12
#undef STAGEALL
#undef STAGEH

  // ---- epilogue (swapped layout): lane (fr,cq) frag (m,n) holds C cols
  // wn+n*16+cq*4 .. +3 at row wm+m*16+fr -> one float4 store each. ----
#pragma unroll
  for (int n = 0; n < 4; ++n) {
    const int colb = bn0 + wn + n * 16 + cq * 4;
    const float4 bv = *(const float4*)(bias + colb);
#pragma unroll
    for (int m = 0; m < 8; ++m) {
      const int row = bm0 + wm + m * 16 + fr;
      float4 v;
      v.x = acc[m][n][0] + bv.x;
      v.y = acc[m][n][1] + bv.y;
      v.z = acc[m][n][2] + bv.z;
      v.w = acc[m][n][3] + bv.w;
      *(float4*)(C + (size_t)row * Mn + colb) = v;
    }
  }
}

extern "C" void kernel_launch(void* const* d_in, const int* in_sizes, int n_in,
                              void* d_out, int out_size, void* d_ws, size_t ws_size,
                              hipStream_t stream) {
  const float* x     = (const float*)d_in[0];
  const float* dw    = (const float*)d_in[1];
  const float* bias  = (const float*)d_in[2];
  const float* sv    = (const float*)d_in[3];
  const int*   rows  = (const int*)d_in[4];
  const int*   cols  = (const int*)d_in[5];
  float* out = (float*)d_out;

  const int  Mn = in_sizes[2];                       // 4096
  const long wElems = (long)in_sizes[1];             // M*K
  const int  K  = (int)(wElems / Mn);                // 4096
  const long xElems = (long)in_sizes[0];             // T*K
  const int  Tm = (int)(xElems / K);                 // 8192
  const int  nnz = in_sizes[3];

  unsigned short* Wb = (unsigned short*)d_ws;        // [M*K] bf16
  unsigned short* Xb = Wb + wElems;                  // [T*K] bf16

  cvt_both<<<2048, 256, 0, stream>>>(dw, Wb, x, Xb, wElems / 8,
                                     (wElems + xElems) / 8);
  sparse_scatter<<<(nnz + 255) / 256, 256, 0, stream>>>(dw, sv, rows, cols, Wb, nnz, K);

  dim3 grid((Tm >> 8) * (Mn >> 8));                  // 32*16 = 512
  gemm17<<<grid, 512, 131072, stream>>>(Xb, Wb, bias, out, Tm, Mn, K);
}

// Round 18
// 296.457 us; speedup vs baseline: 1.0527x; 1.0527x over previous
//
#include <hip/hip_runtime.h>

// SparseWeights: y = x @ (W_dense + scatter(sparse))^T + bias
// Round 18: union of best-measured components. GEMM = r17's gemm17 (lead-1
// counted-lgkm pipeline, swapped-operand float4 epilogue, setprio) — fastest
// GEMM dispatch of the session (268-270us). Prepass = r16's two SEPARATE
// cvt kernels (measured at HBM peak ~6.2-6.5 TB/s; r17's fused cvt_both
// regressed ~15-20us and is reverted) + scatter.

typedef __attribute__((ext_vector_type(8))) __bf16 bf16x8;
typedef __attribute__((ext_vector_type(4))) float f32x4;
typedef __attribute__((ext_vector_type(8))) unsigned short u16x8;

#define BARRIER()   asm volatile("s_barrier" ::: "memory")
#define WAITLGKM(n) asm volatile("s_waitcnt lgkmcnt(" #n ")" ::: "memory")
#define WAITVM0()   asm volatile("s_waitcnt vmcnt(0)" ::: "memory")
#define SCHED0()    __builtin_amdgcn_sched_barrier(0)

__device__ __forceinline__ unsigned short f2bf(float f) {
  unsigned int u = __builtin_bit_cast(unsigned int, f);
  u += 0x7FFFu + ((u >> 16) & 1u);   // round-to-nearest-even
  return (unsigned short)(u >> 16);
}

// ---- prepass 1/3: f32 -> bf16 bulk convert (vectorized x8) ----
__global__ __launch_bounds__(256) void cvt_f32_bf16(
    const float* __restrict__ s, unsigned short* __restrict__ d, long n8) {
  long i = (long)blockIdx.x * blockDim.x + threadIdx.x;
  const long stride = (long)gridDim.x * blockDim.x;
  for (; i < n8; i += stride) {
    const float4* sp = (const float4*)(s + i * 8);
    float4 a = sp[0];
    float4 b = sp[1];
    u16x8 o;
    o[0] = f2bf(a.x); o[1] = f2bf(a.y); o[2] = f2bf(a.z); o[3] = f2bf(a.w);
    o[4] = f2bf(b.x); o[5] = f2bf(b.y); o[6] = f2bf(b.z); o[7] = f2bf(b.w);
    *(u16x8*)(d + i * 8) = o;
  }
}

// ---- prepass 2/3: scatter sparse values into bf16 W (after W-cvt) ----
__global__ __launch_bounds__(256) void sparse_scatter(
    const float* __restrict__ dense, const float* __restrict__ vals,
    const int* __restrict__ rows, const int* __restrict__ cols,
    unsigned short* __restrict__ Wb, int nnz, int K) {
  int i = blockIdx.x * blockDim.x + threadIdx.x;
  if (i < nnz) {
    size_t off = (size_t)rows[i] * (size_t)K + (size_t)cols[i];
    Wb[off] = f2bf(dense[off] + vals[i]);
  }
}

// =====================================================================
// 256x256 GEMM, 512 threads = 8 waves (2Mx4N), wave tile 128x64 =
// acc[8][4] of 16x16x32 frags, BK=64 (kk=0,1). LDS 2 x (A 32K + B 32K)
// = 128 KiB dbuf. Rows 128 B = 8 quads; LDS quad q of row r holds global
// quad q^(r&7) (pre-swizzled source, swizzled read; 0 conflicts r6-r17).
//
// Lead-1 pipeline per tile t (buf = t&1):
//  X1 (end of prev iter): MFMA Q11(t-1); read a03(t)+b01(t) [12];
//     stage-all(t+2) [8 gl_lds]
//  X2: read b23(t) [4]; lgkm(4) {drains 12, keeps b23}; Q00
//  X3: lgkm(0) {b23, covered}; Q01; read a47(t) [8] into shared A-buf
//  X4: lgkm(0) {a47}; Q10; vmcnt(0) {stage(t+1), 1 iter old}; BARRIER
//
// MFMA operands swapped: acc = mfma(b, a, acc) -> lane holds 4
// consecutive C columns -> float4 C-stores. setprio around quadrants.
// =====================================================================
__global__ __launch_bounds__(512, 2) void gemm18(
    const unsigned short* __restrict__ A,   // [Tm][K] bf16
    const unsigned short* __restrict__ B,   // [Mn][K] bf16
    const float* __restrict__ bias,
    float* __restrict__ C,
    int Tm, int Mn, int K) {
  extern __shared__ __align__(16) char smem[];   // 2 x 65536

  const int tid  = threadIdx.x;
  const int lane = tid & 63;
  const int wid  = tid >> 6;
  const int wm = (wid >> 2) * 128;
  const int wn = (wid & 3) * 64;

  // T1: XCD-aware bijective swizzle (nwg = 512, % 8 == 0)
  const int nwg = gridDim.x;
  int bid = blockIdx.x;
  if ((nwg & 7) == 0) bid = (bid & 7) * (nwg >> 3) + (bid >> 3);
  const int ntn = Mn >> 8;
  const int bm0 = (bid / ntn) << 8;
  const int bn0 = (bid % ntn) << 8;

  const int NT = K >> 6;             // K-tiles of 64

  // ---- staging (identical mapping to r6-r17, correctness-verified) ----
  const int sr  = tid >> 3;                          // 0..63
  const int gq8 = ((tid & 7) ^ (sr & 7)) * 8;        // pre-swizzled elem off
  const unsigned short* Asrc = A + (size_t)(bm0 + sr) * K + gq8;
  const unsigned short* Bsrc = B + (size_t)(bn0 + sr) * K + gq8;
  const size_t r64 = (size_t)64 * K;
  const int ldst = tid * 16;

#define STAGEH(SRC, H, LDSB, KOFF) do {                                          \
    __builtin_amdgcn_global_load_lds(                                            \
      (const __attribute__((address_space(1))) void*)((SRC) + (size_t)(H)*2*r64 + (KOFF)), \
      (__attribute__((address_space(3))) void*)(smem + (LDSB) + ldst), 16, 0, 0);\
    __builtin_amdgcn_global_load_lds(                                            \
      (const __attribute__((address_space(1))) void*)((SRC) + (size_t)(H)*2*r64 + r64 + (KOFF)), \
      (__attribute__((address_space(3))) void*)(smem + (LDSB) + 8192 + ldst), 16, 0, 0); \
  } while (0)

#define STAGEALL(NB, KO) do {                                                    \
    STAGEH(Asrc, 0, (NB), (KO));                                                 \
    STAGEH(Asrc, 1, (NB) + 16384, (KO));                                         \
    STAGEH(Bsrc, 0, (NB) + 32768, (KO));                                         \
    STAGEH(Bsrc, 1, (NB) + 49152, (KO));                                         \
  } while (0)

  // ---- read offsets: frag (row R, kk, cq) -> byte R*128 + ((kk*4+cq)^(R&7))*16
  const int fr = lane & 15, cq = lane >> 4;
  const int f7 = fr & 7;
  const int q0 = ((cq ^ f7) << 4);          // kk = 0
  const int q1 = (((4 + cq) ^ f7) << 4);    // kk = 1
  const int arow = (wm + fr) * 128;
  const int brow = (wn + fr) * 128;

  f32x4 acc[8][4] = {};
  bf16x8 Aq0[4], Aq1[4];                    // shared a03 / a47
  bf16x8 b1q0[2], b1q1[2], b2q0[2], b2q1[2];

#define READ12(BUF) do {                                                         \
    _Pragma("unroll")                                                            \
    for (int m = 0; m < 4; ++m) {                                                \
      Aq0[m] = *(const bf16x8*)((BUF) + arow + m * 2048 + q0);                   \
      Aq1[m] = *(const bf16x8*)((BUF) + arow + m * 2048 + q1);                   \
    }                                                                            \
    _Pragma("unroll")                                                            \
    for (int n = 0; n < 2; ++n) {                                                \
      b1q0[n] = *(const bf16x8*)((BUF) + 32768 + brow + n * 2048 + q0);          \
      b1q1[n] = *(const bf16x8*)((BUF) + 32768 + brow + n * 2048 + q1);          \
    }                                                                            \
  } while (0)

#define READB23(BUF) do {                                                        \
    _Pragma("unroll")                                                            \
    for (int n = 0; n < 2; ++n) {                                                \
      b2q0[n] = *(const bf16x8*)((BUF) + 32768 + brow + (n + 2) * 2048 + q0);    \
      b2q1[n] = *(const bf16x8*)((BUF) + 32768 + brow + (n + 2) * 2048 + q1);    \
    }                                                                            \
  } while (0)

#define READA47(BUF) do {                                                        \
    _Pragma("unroll")                                                            \
    for (int m = 0; m < 4; ++m) {                                                \
      Aq0[m] = *(const bf16x8*)((BUF) + arow + (m + 4) * 2048 + q0);             \
      Aq1[m] = *(const bf16x8*)((BUF) + arow + (m + 4) * 2048 + q1);             \
    }                                                                            \
  } while (0)

// Swapped operands + setprio: D = b x a = C^T fragment.
#define QUAD(MB, NB, BQ0, BQ1) do {                                              \
    __builtin_amdgcn_s_setprio(1);                                               \
    _Pragma("unroll")                                                            \
    for (int m = 0; m < 4; ++m)                                                  \
      _Pragma("unroll")                                                          \
      for (int n = 0; n < 2; ++n) {                                              \
        acc[m+(MB)][n+(NB)] = __builtin_amdgcn_mfma_f32_16x16x32_bf16(           \
            BQ0[n], Aq0[m], acc[m+(MB)][n+(NB)], 0, 0, 0);                       \
        acc[m+(MB)][n+(NB)] = __builtin_amdgcn_mfma_f32_16x16x32_bf16(           \
            BQ1[n], Aq1[m], acc[m+(MB)][n+(NB)], 0, 0, 0);                       \
      }                                                                          \
    __builtin_amdgcn_s_setprio(0);                                               \
  } while (0)

  // ---- prologue: stage tile 0; publish; lead-1 reads of tile 0; stage 1 ----
  STAGEALL(0, 0);
  WAITVM0();
  BARRIER();
  READ12(smem);
  SCHED0();
  if (NT > 1) STAGEALL(65536, 64);
  SCHED0();

  for (int t = 0; t < NT; ++t) {
    const char* buf = smem + (t & 1) * 65536;

    // ---- X2: b23 reads; counted lgkm(4); Q00 ----
    READB23(buf);
    SCHED0();
    WAITLGKM(4);          // drain a03+b01 (12); b23 (4) stays in flight
    SCHED0();
    QUAD(0, 0, b1q0, b1q1);
    SCHED0();

    // ---- X3: lgkm(0) (b23, covered by Q00); Q01; a47 reads after ----
    WAITLGKM(0);
    SCHED0();
    QUAD(0, 2, b2q0, b2q1);
    SCHED0();
    READA47(buf);         // overwrites shared A after Q01 latched a03
    SCHED0();

    // ---- X4: lgkm(0) (a47); Q10; drain stages; publish ----
    WAITLGKM(0);
    SCHED0();
    QUAD(4, 0, b1q0, b1q1);
    WAITVM0();            // stage(t+1): issued one full iter ago -> free
    BARRIER();

    // ---- X1 of next frame: Q11; lead-1 reads(t+1); stage(t+2) ----
    QUAD(4, 2, b2q0, b2q1);
    SCHED0();
    if (t + 1 < NT) {
      const char* nbuf = smem + ((t + 1) & 1) * 65536;
      READ12(nbuf);       // overwrites A (a47 latched by Q11) + b01
      SCHED0();
      if (t + 2 < NT) STAGEALL((t & 1) * 65536, (t + 2) * 64);
      SCHED0();
    }
  }
#undef QUAD
#undef READA47
#undef READB23
#undef READ12
#undef STAGEALL
#undef STAGEH

  // ---- epilogue (swapped layout): lane (fr,cq) frag (m,n) holds C cols
  // wn+n*16+cq*4 .. +3 at row wm+m*16+fr -> one float4 store each. ----
#pragma unroll
  for (int n = 0; n < 4; ++n) {
    const int colb = bn0 + wn + n * 16 + cq * 4;
    const float4 bv = *(const float4*)(bias + colb);
#pragma unroll
    for (int m = 0; m < 8; ++m) {
      const int row = bm0 + wm + m * 16 + fr;
      float4 v;
      v.x = acc[m][n][0] + bv.x;
      v.y = acc[m][n][1] + bv.y;
      v.z = acc[m][n][2] + bv.z;
      v.w = acc[m][n][3] + bv.w;
      *(float4*)(C + (size_t)row * Mn + colb) = v;
    }
  }
}

extern "C" void kernel_launch(void* const* d_in, const int* in_sizes, int n_in,
                              void* d_out, int out_size, void* d_ws, size_t ws_size,
                              hipStream_t stream) {
  const float* x     = (const float*)d_in[0];
  const float* dw    = (const float*)d_in[1];
  const float* bias  = (const float*)d_in[2];
  const float* sv    = (const float*)d_in[3];
  const int*   rows  = (const int*)d_in[4];
  const int*   cols  = (const int*)d_in[5];
  float* out = (float*)d_out;

  const int  Mn = in_sizes[2];                       // 4096
  const long wElems = (long)in_sizes[1];             // M*K
  const int  K  = (int)(wElems / Mn);                // 4096
  const long xElems = (long)in_sizes[0];             // T*K
  const int  Tm = (int)(xElems / K);                 // 8192
  const int  nnz = in_sizes[3];

  unsigned short* Wb = (unsigned short*)d_ws;        // [M*K] bf16
  unsigned short* Xb = Wb + wElems;                  // [T*K] bf16

  cvt_f32_bf16<<<2048, 256, 0, stream>>>(dw, Wb, wElems / 8);
  sparse_scatter<<<(nnz + 255) / 256, 256, 0, stream>>>(dw, sv, rows, cols, Wb, nnz, K);
  cvt_f32_bf16<<<2048, 256, 0, stream>>>(x, Xb, xElems / 8);

  dim3 grid((Tm >> 8) * (Mn >> 8));                  // 32*16 = 512
  gemm18<<<grid, 512, 131072, stream>>>(Xb, Wb, bias, out, Tm, Mn, K);
}